// Round 1
// baseline (29.915 us; speedup 1.0000x reference)
//
#include <hip/hip_runtime.h>

// CRPS loss: forecasts (N_MEMBERS, P), observation (P), out (P)
// out[p] = mean_j |x_j - y| - (1-eps) * sum_{j,k} |x_j - x_k| / (2 n (n-1))
// with x = max(forecast, CLIP_VALUE).
// Triangle form: sum_{j,k} = 2 * sum_{j<k}, so term2 = tri_sum / (n(n-1)).

constexpr int N_MEMBERS = 50;
constexpr int BLOCK = 256;
constexpr float CLIP_VALUE = -0.26787253f;
constexpr float EPSILON = 1e-4f;

__global__ __launch_bounds__(BLOCK) void crps_kernel(
    const float* __restrict__ forecasts,    // (N_MEMBERS, P)
    const float* __restrict__ observation,  // (P)
    float* __restrict__ out,                // (P)
    int P)
{
    // [member][tid] layout: coalesced global loads, conflict-free LDS reads
    __shared__ float xs[N_MEMBERS][BLOCK];

    const int tid  = threadIdx.x;
    const int base = blockIdx.x * BLOCK;
    const int p    = base + tid;

    #pragma unroll
    for (int m = 0; m < N_MEMBERS; ++m) {
        float v = (p < P) ? forecasts[m * P + p] : 0.0f;
        xs[m][tid] = fmaxf(v, CLIP_VALUE);
    }
    __syncthreads();

    if (p >= P) return;

    const float y = observation[p];

    float t1 = 0.0f;   // sum_j |x_j - y|
    float t2 = 0.0f;   // sum_{j<k} |x_j - x_k|

    for (int j = 0; j < N_MEMBERS; ++j) {
        const float xj = xs[j][tid];
        t1 += fabsf(xj - y);
        for (int k = j + 1; k < N_MEMBERS; ++k) {
            t2 += fabsf(xj - xs[k][tid]);
        }
    }

    const float term1 = t1 * (1.0f / (float)N_MEMBERS);
    const float term2 = t2 * (1.0f / (float)(N_MEMBERS * (N_MEMBERS - 1)));
    out[p] = term1 - (1.0f - EPSILON) * term2;
}

extern "C" void kernel_launch(void* const* d_in, const int* in_sizes, int n_in,
                              void* d_out, int out_size, void* d_ws, size_t ws_size,
                              hipStream_t stream) {
    const float* forecasts   = (const float*)d_in[0];  // (50, 64, 336)
    const float* observation = (const float*)d_in[1];  // (64, 336)
    float* out = (float*)d_out;                        // (64, 336)

    const int P = out_size;  // 64 * 336 = 21504
    const int grid = (P + BLOCK - 1) / BLOCK;

    crps_kernel<<<grid, BLOCK, 0, stream>>>(forecasts, observation, out, P);
}

// Round 2
// 14.905 us; speedup vs baseline: 2.0070x; 2.0070x over previous
//
#include <hip/hip_runtime.h>

// CRPS loss: forecasts (N_MEMBERS, P), observation (P), out (P)
// out[p] = mean_j |x_j - y| - (1-eps) * sum_{j,k} |x_j - x_k| / (2 n (n-1))
// with x = max(forecast, CLIP_VALUE).
// Triangle form: sum_{j,k} = 2 * sum_{j<k}, so term2 = tri_sum / (n(n-1)).
//
// All 50 member values live in registers (fully unrolled, static indexing).
// 4 rotating accumulators break the dependent-add chain (sum of |.| values,
// reassociation-safe within fp32 tolerance).

constexpr int N_MEMBERS = 50;
constexpr int BLOCK = 64;
constexpr float CLIP_VALUE = -0.26787253f;
constexpr float EPSILON = 1e-4f;

__global__ __launch_bounds__(BLOCK) void crps_kernel(
    const float* __restrict__ forecasts,    // (N_MEMBERS, P)
    const float* __restrict__ observation,  // (P)
    float* __restrict__ out,                // (P)
    int P)
{
    const int p = blockIdx.x * BLOCK + threadIdx.x;
    if (p >= P) return;

    // Load all members into registers (coalesced per member: lane i -> p+i)
    float x[N_MEMBERS];
    #pragma unroll
    for (int m = 0; m < N_MEMBERS; ++m) {
        x[m] = fmaxf(forecasts[m * P + p], CLIP_VALUE);
    }

    const float y = observation[p];

    // term1: sum_j |x_j - y|, 2 accumulators
    float t1a = 0.0f, t1b = 0.0f;
    #pragma unroll
    for (int j = 0; j < N_MEMBERS; j += 2) {
        t1a += fabsf(x[j] - y);
        if (j + 1 < N_MEMBERS) t1b += fabsf(x[j + 1] - y);
    }

    // term2 triangle: sum_{j<k} |x_j - x_k|, 4 rotating accumulators
    float acc0 = 0.0f, acc1 = 0.0f, acc2 = 0.0f, acc3 = 0.0f;
    #pragma unroll
    for (int j = 0; j < N_MEMBERS; ++j) {
        #pragma unroll
        for (int k = j + 1; k < N_MEMBERS; ++k) {
            const int c = (j + k) & 3;   // compile-time constant after unroll
            const float d = fabsf(x[j] - x[k]);
            if      (c == 0) acc0 += d;
            else if (c == 1) acc1 += d;
            else if (c == 2) acc2 += d;
            else             acc3 += d;
        }
    }
    const float t2 = (acc0 + acc1) + (acc2 + acc3);

    const float term1 = (t1a + t1b) * (1.0f / (float)N_MEMBERS);
    const float term2 = t2 * (1.0f / (float)(N_MEMBERS * (N_MEMBERS - 1)));
    out[p] = term1 - (1.0f - EPSILON) * term2;
}

extern "C" void kernel_launch(void* const* d_in, const int* in_sizes, int n_in,
                              void* d_out, int out_size, void* d_ws, size_t ws_size,
                              hipStream_t stream) {
    const float* forecasts   = (const float*)d_in[0];  // (50, 64, 336)
    const float* observation = (const float*)d_in[1];  // (64, 336)
    float* out = (float*)d_out;                        // (64, 336)

    const int P = out_size;  // 64 * 336 = 21504
    const int grid = (P + BLOCK - 1) / BLOCK;

    crps_kernel<<<grid, BLOCK, 0, stream>>>(forecasts, observation, out, P);
}